// Round 5
// baseline (228.221 us; speedup 1.0000x reference)
//
#include <hip/hip_runtime.h>
#include <cstdint>
#include <cstddef>

// ConcreteLayer forward: out = x @ softmax_rows((W + gumbel(U))/T)
// Reformulation v2 (dependency-broken):
//   e[i,k]   = exp((W+G)/T)          (stored bf16, UNSCALED, transposed -> BT [OUT,IN])
//   dpart[t,i] = partial row sums of e over OUT-tile t   (non-atomic, exclusive writes)
//   bt_scale:  BT[k,i] *= 1/sum_t dpart[t,i]             (16 MB pass)
//   out = bf16(x) @ BT                                   (256^2 8-phase MFMA GEMM, split-K=4)
// B=4096, IN=4096, OUT=1024.
// ws: xb (bf16 x, 32MB) | bt (bf16 e^T [OUT,IN], 8MB) | dpart ([16][4096] f32, 256KB)

#define TINYF 1.17549435082228750797e-38f
#define LN2F 0.69314718055994530942f
#define LOG2EF 1.44269504088896340736f

typedef unsigned short u16;
typedef __attribute__((ext_vector_type(8))) short bf16x8;
typedef __attribute__((ext_vector_type(4))) float f32x4;

__device__ __forceinline__ u16 f2bf(float f) {
  union { float f; uint32_t u; } v; v.f = f;
  uint32_t r = v.u + 0x7FFFu + ((v.u >> 16) & 1u);  // RNE
  return (u16)(r >> 16);
}
__device__ __forceinline__ float bf2f(u16 h) {
  union { float f; uint32_t u; } v; v.u = ((uint32_t)h) << 16;
  return v.f;
}

__device__ __forceinline__ float log2_hw(float x) { return __builtin_amdgcn_logf(x); }
__device__ __forceinline__ float exp2_hw(float x) { return __builtin_amdgcn_exp2f(x); }

// g = -ln(-ln(u)) = -ln2 * log2(ln2 * (-log2 u))
__device__ __forceinline__ float gumbel_fast(float u) {
  float t = -log2_hw(u);
  return -LN2F * log2_hw(t * LN2F);
}
__device__ __forceinline__ float exp_fast(float x) { return exp2_hw(x * LOG2EF); }

__device__ __forceinline__ void gld_lds16(const void* g, void* l) {
  __builtin_amdgcn_global_load_lds(
      (__attribute__((address_space(1))) void*)(g),
      (__attribute__((address_space(3))) void*)(l), 16, 0, 0);
}

// ---------------- kernel 1: fused prep ----------------
// blocks [0, 1024): 64x64 exp-transpose tiles of l -> BT (unscaled) + dpart sums
// blocks [1024, 1024+16384): x f32 -> bf16 cast (no scaling)
// blocks [1024+16384, +4096): zero out (split-K accumulator)
#define NB_TRANS 1024
#define NB_CAST 16384
#define NB_ZERO 4096

__global__ void prep_kernel(const float* __restrict__ W, const float* __restrict__ U,
                            const float* __restrict__ Tp, const float4* __restrict__ x,
                            u16* __restrict__ BT, float* __restrict__ dpart,
                            ushort4* __restrict__ xb, float4* __restrict__ out) {
  __shared__ float tile[64][65];
  const int bx = blockIdx.x;
  const int t = threadIdx.x;

  if (bx < NB_TRANS) {
    // ---- exp-transpose tile: k0 = IN-row tile (64 of them), n0 = OUT-col tile (16)
    const int k0 = (bx & 63) * 64, n0 = (bx >> 6) * 64;
    const float invT = 1.0f / Tp[0];
    {
      const int nn4 = (t & 15) * 4, kq = t >> 4;  // 16 rows per pass, float4 cols
#pragma unroll
      for (int r = 0; r < 4; ++r) {
        int kk = r * 16 + kq;
        size_t gi = (size_t)(k0 + kk) * 1024 + (n0 + nn4);
        float4 w = *(const float4*)&W[gi];
        float4 u = *(const float4*)&U[gi];
        float e0 = exp_fast((w.x + gumbel_fast(u.x * (1.0f - TINYF) + TINYF)) * invT);
        float e1 = exp_fast((w.y + gumbel_fast(u.y * (1.0f - TINYF) + TINYF)) * invT);
        float e2 = exp_fast((w.z + gumbel_fast(u.z * (1.0f - TINYF) + TINYF)) * invT);
        float e3 = exp_fast((w.w + gumbel_fast(u.w * (1.0f - TINYF) + TINYF)) * invT);
        tile[kk][nn4 + 0] = e0; tile[kk][nn4 + 1] = e1;
        tile[kk][nn4 + 2] = e2; tile[kk][nn4 + 3] = e3;
        // partial row sum over this thread's 4 cols; reduce across 16 lanes sharing kk
        float s = (e0 + e1) + (e2 + e3);
#pragma unroll
        for (int m = 8; m > 0; m >>= 1) s += __shfl_xor(s, m, 16);
        // exclusive (n-tile, row) slot: no atomics, no pre-zeroing needed
        if ((t & 15) == 0) dpart[(bx >> 6) * 4096 + k0 + kk] = s;
      }
    }
    __syncthreads();
    {
      const int kk4 = (t & 15) * 4, nq = t >> 4;
#pragma unroll
      for (int r = 0; r < 4; ++r) {
        int nn = r * 16 + nq;
        ushort4 o;
        o.x = f2bf(tile[kk4 + 0][nn]);
        o.y = f2bf(tile[kk4 + 1][nn]);
        o.z = f2bf(tile[kk4 + 2][nn]);
        o.w = f2bf(tile[kk4 + 3][nn]);
        *(ushort4*)&BT[(size_t)(n0 + nn) * 4096 + (k0 + kk4)] = o;
      }
    }
  } else if (bx < NB_TRANS + NB_CAST) {
    // ---- x f32 -> bf16 (unscaled; 1/d lives on the BT side)
    int i = (bx - NB_TRANS) * 256 + t;
    float4 v = x[i];
    ushort4 o;
    o.x = f2bf(v.x); o.y = f2bf(v.y); o.z = f2bf(v.z); o.w = f2bf(v.w);
    xb[i] = o;
  } else {
    // ---- zero split-K accumulator
    int j = (bx - NB_TRANS - NB_CAST) * 256 + t;
    out[j] = make_float4(0.f, 0.f, 0.f, 0.f);
  }
}

// ---------------- kernel 2: BT[k,i] *= 1/d_i ----------------
__global__ void bt_scale_kernel(u16* __restrict__ BT, const float* __restrict__ dpart) {
  __shared__ float invd[128];
  const int c0 = blockIdx.x * 128;  // IN col tile (32)
  const int r0 = blockIdx.y * 128;  // OUT row tile (8)
  const int t = threadIdx.x;
  if (t < 128) {
    float s = 0.f;
#pragma unroll
    for (int p = 0; p < 16; ++p) s += dpart[p * 4096 + c0 + t];
    invd[t] = 1.0f / s;
  }
  __syncthreads();
  const int cv = (t & 15) * 8, rq = t >> 4;
  const float4 ia = *(const float4*)&invd[cv];
  const float4 ib = *(const float4*)&invd[cv + 4];
#pragma unroll
  for (int pass = 0; pass < 8; ++pass) {
    int row = r0 + pass * 16 + rq;
    size_t gi = (size_t)row * 4096 + c0 + cv;
    ushort4 a = *(ushort4*)&BT[gi];
    ushort4 b = *(ushort4*)&BT[gi + 4];
    ushort4 oa, ob;
    oa.x = f2bf(bf2f(a.x) * ia.x); oa.y = f2bf(bf2f(a.y) * ia.y);
    oa.z = f2bf(bf2f(a.z) * ia.z); oa.w = f2bf(bf2f(a.w) * ia.w);
    ob.x = f2bf(bf2f(b.x) * ib.x); ob.y = f2bf(bf2f(b.y) * ib.y);
    ob.z = f2bf(bf2f(b.z) * ib.z); ob.w = f2bf(bf2f(b.w) * ib.w);
    *(ushort4*)&BT[gi] = oa;
    *(ushort4*)&BT[gi + 4] = ob;
  }
}

// ---------------- kernel 3: 256x256 8-phase GEMM, BK=64, split-K=4 ----------------
// 8 waves (2M x 4N), 512 threads, per-wave output 128x64. LDS 128KB dynamic:
// 2 dbuf x 4 half-tile slots (A-lo, A-hi, B-lo, B-hi; 16KB each).
// Per K-tile (BK=64): 4 phases, quadrant schedule. Reads of tile T happen at its
// P1 (A-lo quads + B first) / P2 (B second) / P3 (A-hi quads); P4 has no reads.
// STAGE CADENCE (R5 fix — the R4 regression was a 1-phase stage->wait lead):
//   P1: stage hts 2,3 (B halves) of tile T+1   -> guaranteed at T's P4  (3-phase lead)
//   P4: stage hts 0,1 (A halves) of tile T+2   -> guaranteed at T+1's P4 (4-phase lead)
//   vmcnt(4) ONCE per tile at P4: leaves exactly the newest pair (4 ops) in flight,
//   guaranteeing tile T+1 fully landed before its reads at the next phase.
// In-flight profile: 4 ops entering P1 -> 8 after P1 -> 12 after P4 -> drain to 4.
// LDS race audit: P4's write target (dbuf T&1, A slots) was last read at T's P3 —
// all waves completed those ds_reads (per-phase lgkmcnt(0)) before P3's closing
// barrier. P1's write target is the opposite-parity buffer, last read a full tile
// ago. Tail stages: parity from the LOGICAL tile index (dead buffer), data clamped.
// Swizzle: LDS granule g of row r holds global granule g^(r&7) (proven in the 128^2
// kernel, bank-conflict counter = 0): staging pre-swizzles the GLOBAL column, LDS
// stays lane-linear (gld_lds requirement); ds_read_b128 XORs the granule back.
#define NT 16   // K-tiles per block: (4096/SPLITK)/64
#define NIT 8   // NT/2
#define SPLITK 4

__device__ __forceinline__ void stage_pair(const u16* __restrict__ Ak, const u16* __restrict__ Bk,
                                           int m0, int n0, char* smem, int dtile, int ptile,
                                           int hbase, int w, int lane) {
  char* dbuf = smem + (ptile & 1) * 65536;
  const int rr = lane >> 3;
  const int gcol = dtile * 64 + (((lane & 7) ^ rr) << 3);
#pragma unroll
  for (int h = 0; h < 2; ++h) {
    const int ht = hbase + h;
    const u16* src = (ht < 2) ? (Ak + (size_t)(m0 + ht * 128) * 4096)
                              : (Bk + (size_t)(n0 + (ht - 2) * 128) * 4096);
    char* dst = dbuf + ht * 16384;
#pragma unroll
    for (int c = 0; c < 2; ++c) {
      const int chunk = w * 2 + c;  // 16 chunks x (8 rows x 64 cols) per half-tile
      gld_lds16(src + (size_t)(chunk * 8 + rr) * 4096 + gcol, dst + chunk * 1024);
    }
  }
}

__launch_bounds__(512, 2)
__global__ void gemm_bt_kernel(const u16* __restrict__ A, const u16* __restrict__ BT,
                               float* __restrict__ C) {
  extern __shared__ char smem[];
  // bijective XCD-chunked swizzle (m204): 256 blocks = 8 XCD x 32
  int wg = blockIdx.x;
  wg = (wg & 7) * 32 + (wg >> 3);
  const int kz = wg >> 6;
  const int bx = wg & 15, by = (wg >> 4) & 3;
  const int m0 = bx * 256, n0 = by * 256;
  const int tid = threadIdx.x, lane = tid & 63, w = tid >> 6;
  const int wm = w >> 2, wn = w & 3;  // 2x4 wave grid; per-wave 128 rows x 64 cols
  const int r16 = lane & 15, quad = lane >> 4, r7 = r16 & 7;

  const u16* Ak = A + (size_t)kz * 1024;
  const u16* Bk = BT + (size_t)kz * 1024;

  // frag read bases: each wave touches only its A-half slot and B-half slot
  char* abase = smem + wm * 16384 + r16 * 128;
  char* bbase = smem + 32768 + (wn >> 1) * 16384 + ((wn & 1) * 64 + r16) * 128;
  const int gx[2] = {(quad ^ r7) * 16, ((4 + quad) ^ r7) * 16};  // granule: ss*4+quad

  bf16x8 aF[4][2], bF[4][2];
  f32x4 acc[8][4] = {};

#define RD_A(DB, MB)                                                              \
  _Pragma("unroll") for (int j = 0; j < 4; ++j) {                                 \
    aF[j][0] = *(const bf16x8*)(abase + (DB) * 65536 + ((MB) + j) * 2048 + gx[0]); \
    aF[j][1] = *(const bf16x8*)(abase + (DB) * 65536 + ((MB) + j) * 2048 + gx[1]); \
  }
#define RD_B(DB, NB)                                                                   \
  _Pragma("unroll") for (int j = 0; j < 2; ++j) {                                      \
    bF[(NB) + j][0] = *(const bf16x8*)(bbase + (DB) * 65536 + ((NB) + j) * 2048 + gx[0]); \
    bF[(NB) + j][1] = *(const bf16x8*)(bbase + (DB) * 65536 + ((NB) + j) * 2048 + gx[1]); \
  }
#define MM(MB, NB)                                                                \
  _Pragma("unroll") for (int mi = 0; mi < 4; ++mi)                                \
    _Pragma("unroll") for (int nj = 0; nj < 2; ++nj) {                            \
      acc[(MB) + mi][(NB) + nj] = __builtin_amdgcn_mfma_f32_16x16x32_bf16(        \
          aF[mi][0], bF[(NB) + nj][0], acc[(MB) + mi][(NB) + nj], 0, 0, 0);       \
      acc[(MB) + mi][(NB) + nj] = __builtin_amdgcn_mfma_f32_16x16x32_bf16(        \
          aF[mi][1], bF[(NB) + nj][1], acc[(MB) + mi][(NB) + nj], 0, 0, 0);       \
    }
#define SP(DT, PT, HB)                                                            \
  {                                                                               \
    int dc = (DT) < (NT - 1) ? (DT) : (NT - 1);                                   \
    stage_pair(Ak, Bk, m0, n0, smem, dc, (PT), (HB), w, lane);                    \
  }
#define VM4 asm volatile("s_waitcnt vmcnt(4)" ::: "memory");
#define PH(READS, STAGES, MFMAS, WAIT)                                            \
  {                                                                               \
    READS                                                                         \
    STAGES                                                                        \
    __builtin_amdgcn_s_barrier();                                                 \
    asm volatile("s_waitcnt lgkmcnt(0)" ::: "memory");                            \
    __builtin_amdgcn_sched_barrier(0);                                            \
    __builtin_amdgcn_s_setprio(1);                                                \
    MFMAS                                                                         \
    __builtin_amdgcn_s_setprio(0);                                                \
    WAIT                                                                          \
    __builtin_amdgcn_s_barrier();                                                 \
  }

  // prologue: tile0 fully + tile1 A-halves; vmcnt(4) guarantees tile0, leaves
  // tile1 ht0,ht1 in flight — matches the steady-state P1 entry invariant.
  stage_pair(Ak, Bk, m0, n0, smem, 0, 0, 0, w, lane);
  stage_pair(Ak, Bk, m0, n0, smem, 0, 0, 2, w, lane);
  stage_pair(Ak, Bk, m0, n0, smem, 1, 1, 0, w, lane);
  VM4
  __builtin_amdgcn_s_barrier();

  for (int i = 0; i < NIT; ++i) {
    const int tb = 2 * i + 1;
    // tile 2i (dbuf 0)
    PH(RD_A(0, 0) RD_B(0, 0), SP(tb, tb, 2),         MM(0, 0), )
    PH(RD_B(0, 2),            ,                      MM(0, 2), )
    PH(RD_A(0, 4),            ,                      MM(4, 2), )
    PH(,                      SP(tb + 1, tb + 1, 0), MM(4, 0), VM4)
    // tile 2i+1 (dbuf 1)
    PH(RD_A(1, 0) RD_B(1, 0), SP(tb + 1, tb + 1, 2), MM(0, 0), )
    PH(RD_B(1, 2),            ,                      MM(0, 2), )
    PH(RD_A(1, 4),            ,                      MM(4, 2), )
    PH(,                      SP(tb + 2, tb + 2, 0), MM(4, 0), VM4)
  }
#undef RD_A
#undef RD_B
#undef MM
#undef SP
#undef VM4
#undef PH

  // epilogue: C/D layout col = lane&15, row = quad*4 + reg; split-K accumulate
#pragma unroll
  for (int mi = 0; mi < 8; ++mi)
#pragma unroll
    for (int ni = 0; ni < 4; ++ni)
#pragma unroll
      for (int r = 0; r < 4; ++r) {
        int row = m0 + wm * 128 + mi * 16 + quad * 4 + r;
        int col = n0 + wn * 64 + ni * 16 + r16;
        atomicAdd(&C[(size_t)row * 1024 + col], acc[mi][ni][r]);
      }
}

extern "C" void kernel_launch(void* const* d_in, const int* in_sizes, int n_in,
                              void* d_out, int out_size, void* d_ws, size_t ws_size,
                              hipStream_t stream) {
  const int M = 4096, K = 4096, N = 1024;  // B, IN, OUT
  const float* x = (const float*)d_in[0];
  const float* W = (const float*)d_in[1];
  const float* U = (const float*)d_in[2];
  const float* Tp = (const float*)d_in[3];
  float* out = (float*)d_out;

  char* ws = (char*)d_ws;
  u16* xb = (u16*)ws;                                          // 32 MB
  u16* bt = (u16*)(ws + (size_t)M * K * 2);                    // 8 MB
  float* dpart = (float*)(ws + (size_t)M * K * 2 + (size_t)N * K * 2);  // 256 KB

  static bool attr_done = false;
  if (!attr_done) {
    hipFuncSetAttribute((const void*)gemm_bt_kernel,
                        hipFuncAttributeMaxDynamicSharedMemorySize, 131072);
    attr_done = true;
  }

  prep_kernel<<<dim3(NB_TRANS + NB_CAST + NB_ZERO), 256, 0, stream>>>(
      W, U, Tp, (const float4*)x, bt, dpart, (ushort4*)xb, (float4*)out);
  bt_scale_kernel<<<dim3(32, 8), 256, 0, stream>>>(bt, dpart);
  gemm_bt_kernel<<<dim3(256), 512, 131072, stream>>>(xb, bt, out);
}

// Round 6
// 188.380 us; speedup vs baseline: 1.2115x; 1.2115x over previous
//
#include <hip/hip_runtime.h>
#include <cstdint>
#include <cstddef>

// ConcreteLayer forward: out = x @ softmax_rows((W + gumbel(U))/T)
// Reformulation v2 (dependency-broken):
//   e[i,k]   = exp((W+G)/T)          (stored bf16, UNSCALED, transposed -> BT [OUT,IN])
//   dpart[t,i] = partial row sums of e over OUT-tile t   (non-atomic, exclusive writes)
//   bt_scale:  BT[k,i] *= 1/sum_t dpart[t,i]             (16 MB pass)
//   out = bf16(x) @ BT                                   (MFMA GEMM, split-K=2 atomics)
// B=4096, IN=4096, OUT=1024.
// ws: xb (bf16 x, 32MB) | bt (bf16 e^T [OUT,IN], 8MB) | dpart ([16][4096] f32, 256KB)
//
// GEMM history: 128x128/2blk-CU = 505 TF (R0); split-K4 (R1) regressed via 2x atomics;
// 2-phase dbuf (R2) neutral; 8-phase 256^2 (R4/R5) regressed 3x - within-phase
// read->wait->MFMA serialization, needs fragment dbuf we don't have regs for.
// R6: 128x64 tile, split-K=2 -> 1024 blocks (4/CU offered), 24KB LDS (6 fit),
// acc 32 AGPR (total ~110 regs) - replicates m97's 912TF@4blk condition with
// unchanged atomic count. Theory: this structure's perf scales with co-resident
// blocks (inter-block overlap hides the per-tile vmcnt(0)+barrier drain, m114).

#define TINYF 1.17549435082228750797e-38f
#define LN2F 0.69314718055994530942f
#define LOG2EF 1.44269504088896340736f

typedef unsigned short u16;
typedef __attribute__((ext_vector_type(8))) short bf16x8;
typedef __attribute__((ext_vector_type(4))) float f32x4;

__device__ __forceinline__ u16 f2bf(float f) {
  union { float f; uint32_t u; } v; v.f = f;
  uint32_t r = v.u + 0x7FFFu + ((v.u >> 16) & 1u);  // RNE
  return (u16)(r >> 16);
}
__device__ __forceinline__ float bf2f(u16 h) {
  union { float f; uint32_t u; } v; v.u = ((uint32_t)h) << 16;
  return v.f;
}

__device__ __forceinline__ float log2_hw(float x) { return __builtin_amdgcn_logf(x); }
__device__ __forceinline__ float exp2_hw(float x) { return __builtin_amdgcn_exp2f(x); }

// g = -ln(-ln(u)) = -ln2 * log2(ln2 * (-log2 u))
__device__ __forceinline__ float gumbel_fast(float u) {
  float t = -log2_hw(u);
  return -LN2F * log2_hw(t * LN2F);
}
__device__ __forceinline__ float exp_fast(float x) { return exp2_hw(x * LOG2EF); }

__device__ __forceinline__ void gld_lds16(const void* g, void* l) {
  __builtin_amdgcn_global_load_lds(
      (__attribute__((address_space(1))) void*)(g),
      (__attribute__((address_space(3))) void*)(l), 16, 0, 0);
}

// ---------------- kernel 1: fused prep ----------------
// blocks [0, 1024): 64x64 exp-transpose tiles of l -> BT (unscaled) + dpart sums
// blocks [1024, 1024+16384): x f32 -> bf16 cast (no scaling)
// blocks [1024+16384, +4096): zero out (split-K accumulator)
#define NB_TRANS 1024
#define NB_CAST 16384
#define NB_ZERO 4096

__global__ void prep_kernel(const float* __restrict__ W, const float* __restrict__ U,
                            const float* __restrict__ Tp, const float4* __restrict__ x,
                            u16* __restrict__ BT, float* __restrict__ dpart,
                            ushort4* __restrict__ xb, float4* __restrict__ out) {
  __shared__ float tile[64][65];
  const int bx = blockIdx.x;
  const int t = threadIdx.x;

  if (bx < NB_TRANS) {
    // ---- exp-transpose tile: k0 = IN-row tile (64 of them), n0 = OUT-col tile (16)
    const int k0 = (bx & 63) * 64, n0 = (bx >> 6) * 64;
    const float invT = 1.0f / Tp[0];
    {
      const int nn4 = (t & 15) * 4, kq = t >> 4;  // 16 rows per pass, float4 cols
#pragma unroll
      for (int r = 0; r < 4; ++r) {
        int kk = r * 16 + kq;
        size_t gi = (size_t)(k0 + kk) * 1024 + (n0 + nn4);
        float4 w = *(const float4*)&W[gi];
        float4 u = *(const float4*)&U[gi];
        float e0 = exp_fast((w.x + gumbel_fast(u.x * (1.0f - TINYF) + TINYF)) * invT);
        float e1 = exp_fast((w.y + gumbel_fast(u.y * (1.0f - TINYF) + TINYF)) * invT);
        float e2 = exp_fast((w.z + gumbel_fast(u.z * (1.0f - TINYF) + TINYF)) * invT);
        float e3 = exp_fast((w.w + gumbel_fast(u.w * (1.0f - TINYF) + TINYF)) * invT);
        tile[kk][nn4 + 0] = e0; tile[kk][nn4 + 1] = e1;
        tile[kk][nn4 + 2] = e2; tile[kk][nn4 + 3] = e3;
        // partial row sum over this thread's 4 cols; reduce across 16 lanes sharing kk
        float s = (e0 + e1) + (e2 + e3);
#pragma unroll
        for (int m = 8; m > 0; m >>= 1) s += __shfl_xor(s, m, 16);
        // exclusive (n-tile, row) slot: no atomics, no pre-zeroing needed
        if ((t & 15) == 0) dpart[(bx >> 6) * 4096 + k0 + kk] = s;
      }
    }
    __syncthreads();
    {
      const int kk4 = (t & 15) * 4, nq = t >> 4;
#pragma unroll
      for (int r = 0; r < 4; ++r) {
        int nn = r * 16 + nq;
        ushort4 o;
        o.x = f2bf(tile[kk4 + 0][nn]);
        o.y = f2bf(tile[kk4 + 1][nn]);
        o.z = f2bf(tile[kk4 + 2][nn]);
        o.w = f2bf(tile[kk4 + 3][nn]);
        *(ushort4*)&BT[(size_t)(n0 + nn) * 4096 + (k0 + kk4)] = o;
      }
    }
  } else if (bx < NB_TRANS + NB_CAST) {
    // ---- x f32 -> bf16 (unscaled; 1/d lives on the BT side)
    int i = (bx - NB_TRANS) * 256 + t;
    float4 v = x[i];
    ushort4 o;
    o.x = f2bf(v.x); o.y = f2bf(v.y); o.z = f2bf(v.z); o.w = f2bf(v.w);
    xb[i] = o;
  } else {
    // ---- zero split-K accumulator
    int j = (bx - NB_TRANS - NB_CAST) * 256 + t;
    out[j] = make_float4(0.f, 0.f, 0.f, 0.f);
  }
}

// ---------------- kernel 2: BT[k,i] *= 1/d_i ----------------
__global__ void bt_scale_kernel(u16* __restrict__ BT, const float* __restrict__ dpart) {
  __shared__ float invd[128];
  const int c0 = blockIdx.x * 128;  // IN col tile (32)
  const int r0 = blockIdx.y * 128;  // OUT row tile (8)
  const int t = threadIdx.x;
  if (t < 128) {
    float s = 0.f;
#pragma unroll
    for (int p = 0; p < 16; ++p) s += dpart[p * 4096 + c0 + t];
    invd[t] = 1.0f / s;
  }
  __syncthreads();
  const int cv = (t & 15) * 8, rq = t >> 4;
  const float4 ia = *(const float4*)&invd[cv];
  const float4 ib = *(const float4*)&invd[cv + 4];
#pragma unroll
  for (int pass = 0; pass < 8; ++pass) {
    int row = r0 + pass * 16 + rq;
    size_t gi = (size_t)row * 4096 + c0 + cv;
    ushort4 a = *(ushort4*)&BT[gi];
    ushort4 b = *(ushort4*)&BT[gi + 4];
    ushort4 oa, ob;
    oa.x = f2bf(bf2f(a.x) * ia.x); oa.y = f2bf(bf2f(a.y) * ia.y);
    oa.z = f2bf(bf2f(a.z) * ia.z); oa.w = f2bf(bf2f(a.w) * ia.w);
    ob.x = f2bf(bf2f(b.x) * ib.x); ob.y = f2bf(bf2f(b.y) * ib.y);
    ob.z = f2bf(bf2f(b.z) * ib.z); ob.w = f2bf(bf2f(b.w) * ib.w);
    *(ushort4*)&BT[gi] = oa;
    *(ushort4*)&BT[gi + 4] = ob;
  }
}

// ---------------- kernel 3: GEMM 128x64 tile, TK=64, XOR-swizzled LDS, split-K=2 ----------------
// 4 waves (2x2 grid), per-wave output 64x32. acc = 4x2 f32x4 = 32 AGPR.
// LDS granule g of row r holds global 16B-granule (g ^ (r&7)) -> fragment ds_read_b128
// hits 8 distinct bank groups (2-way aliasing = free), staging stays lane-contiguous.
// LDS 24KB -> 6 blocks/CU cap; grid 1024 -> 4 blocks/CU offered.
#define TM 128
#define TN 64
#define TK 64
#define SPLITK 2

__launch_bounds__(256)
__global__ void gemm_bt_kernel(const u16* __restrict__ A, const u16* __restrict__ BT,
                               float* __restrict__ C, int M, int N, int K) {
  __shared__ u16 As[TM * TK];  // 16 KB
  __shared__ u16 Bs[TN * TK];  // 8 KB

  const int tid = threadIdx.x;
  const int lane = tid & 63, w = tid >> 6;
  const int wm = w >> 1, wn = w & 1;           // 2x2 wave grid, 64x32 per wave
  const int m0 = blockIdx.x * TM, n0 = blockIdx.y * TN;
  const int quad = lane >> 4, r16 = lane & 15;
  const int srow = lane >> 3;                  // staging: row within 8-row chunk
  const int sg = (lane & 7) ^ srow;            // staging: swizzled 16B granule in row

  const int kz = blockIdx.z;                   // split-K = 2
  const int Kh = K >> 1;
  const u16* Ak = A + (size_t)kz * Kh;
  const u16* Bk = BT + (size_t)kz * Kh;

  f32x4 acc[4][2] = {};

  for (int kt = 0; kt < Kh; kt += TK) {
    __syncthreads();
#pragma unroll
    for (int c = 0; c < 4; ++c) {               // A: 16 chunks of 8 rows x 64 cols (1 KB)
      int chunk = w * 4 + c;
      gld_lds16(Ak + (size_t)(m0 + chunk * 8 + srow) * K + kt + sg * 8, (char*)As + chunk * 1024);
    }
#pragma unroll
    for (int c = 0; c < 2; ++c) {               // B: 8 chunks
      int chunk = w * 2 + c;
      gld_lds16(Bk + (size_t)(n0 + chunk * 8 + srow) * K + kt + sg * 8, (char*)Bs + chunk * 1024);
    }
    __syncthreads();

#pragma unroll
    for (int ss = 0; ss < 2; ++ss) {           // two K=32 sub-steps per staged TK=64
      bf16x8 aF[4], bF[2];
#pragma unroll
      for (int mi = 0; mi < 4; ++mi) {
        int row = wm * 64 + mi * 16 + r16;
        aF[mi] = *(const bf16x8*)((const char*)As + row * 128 + (((ss * 4 + quad) ^ (row & 7)) * 16));
      }
#pragma unroll
      for (int ni = 0; ni < 2; ++ni) {
        int row = wn * 32 + ni * 16 + r16;
        bF[ni] = *(const bf16x8*)((const char*)Bs + row * 128 + (((ss * 4 + quad) ^ (row & 7)) * 16));
      }
#pragma unroll
      for (int mi = 0; mi < 4; ++mi)
#pragma unroll
        for (int ni = 0; ni < 2; ++ni)
          acc[mi][ni] = __builtin_amdgcn_mfma_f32_16x16x32_bf16(aF[mi], bF[ni], acc[mi][ni], 0, 0, 0);
    }
  }

  // epilogue: C/D layout col = lane&15, row = quad*4 + reg
#pragma unroll
  for (int mi = 0; mi < 4; ++mi)
#pragma unroll
    for (int ni = 0; ni < 2; ++ni)
#pragma unroll
      for (int r = 0; r < 4; ++r) {
        int row = m0 + wm * 64 + mi * 16 + quad * 4 + r;
        int col = n0 + wn * 32 + ni * 16 + r16;
        atomicAdd(&C[(size_t)row * N + col], acc[mi][ni][r]);
      }
}

extern "C" void kernel_launch(void* const* d_in, const int* in_sizes, int n_in,
                              void* d_out, int out_size, void* d_ws, size_t ws_size,
                              hipStream_t stream) {
  const int M = 4096, K = 4096, N = 1024;  // B, IN, OUT
  const float* x = (const float*)d_in[0];
  const float* W = (const float*)d_in[1];
  const float* U = (const float*)d_in[2];
  const float* Tp = (const float*)d_in[3];
  float* out = (float*)d_out;

  char* ws = (char*)d_ws;
  u16* xb = (u16*)ws;                                          // 32 MB
  u16* bt = (u16*)(ws + (size_t)M * K * 2);                    // 8 MB
  float* dpart = (float*)(ws + (size_t)M * K * 2 + (size_t)N * K * 2);  // 256 KB

  prep_kernel<<<dim3(NB_TRANS + NB_CAST + NB_ZERO), 256, 0, stream>>>(
      W, U, Tp, (const float4*)x, bt, dpart, (ushort4*)xb, (float4*)out);
  bt_scale_kernel<<<dim3(32, 8), 256, 0, stream>>>(bt, dpart);
  gemm_bt_kernel<<<dim3(M / TM, N / TN, SPLITK), 256, 0, stream>>>(xb, bt, out, M, N, K);
}